// Round 7
// baseline (164.418 us; speedup 1.0000x reference)
//
#include <hip/hip_runtime.h>
#include <math.h>

// Problem constants (match reference)
constexpr int   B_     = 2048;
constexpr int   L_     = 8192;
constexpr int   G_     = 256;
constexpr float BETA_  = 0.01f;
constexpr float BIG_   = 1024.0f;      // y-flag encoding
constexpr int   PMAX   = L_ + G_ * 3;  // padded rank-space bound = 8960
constexpr int   CHUNK  = 2048;         // elements per staged chunk
constexpr int   NCHUNK = L_ / CHUNK;   // 4

// log(sigmoid(-x)) = -softplus(x); HW transcendentals (absmax 0.0 in R2-R6).
__device__ __forceinline__ float log_sigmoid_neg(float x) {
    return -(fmaxf(x, 0.0f) + __logf(1.0f + __expf(-fabsf(x))));
}

// Async global->LDS DMA, 16B per lane. HW semantics: LDS dest = wave-uniform
// base + lane*16; caller passes the wave's base. Fire-and-forget (vmcnt).
__device__ __forceinline__ void dma16(const void* g, void* l) {
    __builtin_amdgcn_global_load_lds(
        (const __attribute__((address_space(1))) void*)g,
        (__attribute__((address_space(3))) void*)l, 16, 0, 0);
}

// ---------------------------------------------------------------------------
// k0: counting sort -> padded rank space (each group's extent rounded up to
// 4 floats so phase 2 can use aligned ds_read_b128; pad slots stay 0).
// ---------------------------------------------------------------------------
extern "C" __global__ __launch_bounds__(1024)
void build_rank_kernel(const int* __restrict__ group_ids,
                       int* __restrict__ g_offs,
                       unsigned short* __restrict__ g_rank)
{
    __shared__ int s_hist[G_];
    __shared__ int s_scan[G_];
    __shared__ int s_cur[G_];

    const int t = threadIdx.x;              // 0..1023

    if (t < G_) s_hist[t] = 0;

    int ids[8];
    #pragma unroll
    for (int i = 0; i < 8; ++i) ids[i] = group_ids[i * 1024 + t];

    __syncthreads();

    #pragma unroll
    for (int i = 0; i < 8; ++i) atomicAdd(&s_hist[ids[i]], 1);
    __syncthreads();

    // inclusive scan over PADDED counts
    if (t < G_) s_scan[t] = (s_hist[t] + 3) & ~3;
    __syncthreads();
    for (int off = 1; off < G_; off <<= 1) {
        int v = 0;
        if (t < G_ && t >= off) v = s_scan[t - off];
        __syncthreads();
        if (t < G_) s_scan[t] += v;
        __syncthreads();
    }

    if (t < G_) {
        const int excl = s_scan[t] - ((s_hist[t] + 3) & ~3);  // padded start
        s_cur[t]  = excl;
        g_offs[t] = excl;
    }
    if (t == 0) g_offs[G_] = s_scan[G_ - 1];
    __syncthreads();

    #pragma unroll
    for (int i = 0; i < 8; ++i) {
        const int l = i * 1024 + t;
        g_rank[l] = (unsigned short)atomicAdd(&s_cur[ids[i]], 1);
    }
}

// ---------------------------------------------------------------------------
// Main kernel, one block (512 thr) per row.
//  R6 post-mortem: VGPR=24 -> <=2 loads in flight -> fetch-latency bound at
//  1.5 TB/s. Fix: stream logits/true_y via global_load_lds (async DMA, no
//  VGPR round-trip), double-buffered chunks. DMA(c+1) is issued BEFORE
//  compute(c); the next iteration's barrier drains it -> HBM overlaps compute.
//  LDS: 35KB s_row + 2*8KB x + 2*8KB y = 67KB -> 2 blocks/CU (16 waves).
// ---------------------------------------------------------------------------
extern "C" __global__ __launch_bounds__(512, 4)
void meta_loss_kernel(const float* __restrict__ logits,
                      const int*   __restrict__ true_y,
                      const int*   __restrict__ g_offs,
                      const unsigned short* __restrict__ g_rank,
                      float*       __restrict__ out)
{
    __shared__ alignas(16) float s_row[PMAX];        // 35 KB permuted encoded row
    __shared__ alignas(16) float s_x[2][CHUNK];      // 2 x 8 KB logits stage
    __shared__ alignas(16) int   s_y[2][CHUNK];      // 2 x 8 KB labels stage
    __shared__ float s_part[8];

    const int t  = threadIdx.x;                      // 0..511
    const int b  = blockIdx.x;
    const int wb = (t & ~63) * 16;                   // wave-uniform byte base in stage

    const float* xrow = logits + (size_t)b * L_;
    const int*   yrow = true_y + (size_t)b * L_;

    // rank prefetch: thread t covers elements 4t..4t+3 of each chunk (L2-hot)
    ushort4 r[NCHUNK];
    const ushort4* rk = (const ushort4*)g_rank;
    #pragma unroll
    for (int c = 0; c < NCHUNK; ++c)
        r[c] = rk[c * (CHUNK / 4) + t];

    int o0 = 0, o1 = 0;
    if (t < G_) { o0 = g_offs[t]; o1 = g_offs[t + 1]; }

    // zero-init padded row (pad slots must be 0)
    float4* s_row4 = (float4*)s_row;
    #pragma unroll
    for (int i = 0; i < (PMAX / 4 + 511) / 512; ++i) {
        const int j = i * 512 + t;
        if (j < PMAX / 4) s_row4[j] = make_float4(0.f, 0.f, 0.f, 0.f);
    }

    // prologue: DMA chunk 0 into buffer 0
    dma16(xrow + 4 * t, (char*)&s_x[0][0] + wb);
    dma16(yrow + 4 * t, (char*)&s_y[0][0] + wb);

    #pragma unroll
    for (int c = 0; c < NCHUNK; ++c) {
        __syncthreads();   // drains DMA(c) (vmcnt 0); compute(c-1) finished

        if (c + 1 < NCHUNK) {   // issue DMA(c+1) now; drained at NEXT barrier
            const int nb = (c + 1) & 1;
            dma16(xrow + (c + 1) * CHUNK + 4 * t, (char*)&s_x[nb][0] + wb);
            dma16(yrow + (c + 1) * CHUNK + 4 * t, (char*)&s_y[nb][0] + wb);
        }

        const int     bu = c & 1;
        const float4  x  = ((const float4*)s_x[bu])[t];
        const int4    y  = ((const int4*)s_y[bu])[t];
        const ushort4 rr = r[c];
        s_row[rr.x] = log_sigmoid_neg(x.x) + (y.x ? BIG_ : 0.0f);
        s_row[rr.y] = log_sigmoid_neg(x.y) + (y.y ? BIG_ : 0.0f);
        s_row[rr.z] = log_sigmoid_neg(x.z) + (y.z ? BIG_ : 0.0f);
        s_row[rr.w] = log_sigmoid_neg(x.w) + (y.w ? BIG_ : 0.0f);
    }
    __syncthreads();

    // ---- Phase 2: vectorized contiguous per-group sum + decode ----
    float term = 0.0f;
    if (t < G_) {
        float4 a4 = make_float4(0.f, 0.f, 0.f, 0.f);
        for (int j = o0; j < o1; j += 4) {
            const float4 v = *(const float4*)&s_row[j];
            a4.x += v.x; a4.y += v.y; a4.z += v.z; a4.w += v.w;
        }
        const float enc = (a4.x + a4.y) + (a4.z + a4.w);

        const int   k  = __float2int_rn(enc * (1.0f / BIG_));  // # true labels
        const float gl = enc - BIG_ * (float)k;                // sum log(1-sig)

        if (k != 0) {
            term = fmaxf(gl, -100.0f);                    // meta_y = 1: log(p)
        } else {
            // gl==0 (empty group) -> log1p(-1) = -inf -> clamped to -100
            term = fmaxf(log1pf(-__expf(gl)), -100.0f);   // meta_y = 0
        }
    }

    // block reduction (8 waves)
    #pragma unroll
    for (int off = 32; off > 0; off >>= 1)
        term += __shfl_down(term, off, 64);
    if ((t & 63) == 0) s_part[t >> 6] = term;
    __syncthreads();

    if (t == 0) {
        float s = 0.0f;
        #pragma unroll
        for (int w = 0; w < 8; ++w) s += s_part[w];
        atomicAdd(out, s * (-BETA_ / ((float)B_ * (float)G_)));
    }
}

extern "C" void kernel_launch(void* const* d_in, const int* in_sizes, int n_in,
                              void* d_out, int out_size, void* d_ws, size_t ws_size,
                              hipStream_t stream) {
    const float* logits    = (const float*)d_in[0];
    const int*   true_y    = (const int*)d_in[1];
    const int*   group_ids = (const int*)d_in[2];
    float*       out       = (float*)d_out;

    // workspace: [0, 2048) offs (257 ints used), [2048, 2048+16384) rank u16
    int*            g_offs = (int*)d_ws;
    unsigned short* g_rank = (unsigned short*)((char*)d_ws + 2048);

    hipMemsetAsync(out, 0, sizeof(float), stream);

    build_rank_kernel<<<1, 1024, 0, stream>>>(group_ids, g_offs, g_rank);
    meta_loss_kernel<<<B_, 512, 0, stream>>>(logits, true_y, g_offs, g_rank, out);
}

// Round 9
// 153.704 us; speedup vs baseline: 1.0697x; 1.0697x over previous
//
#include <hip/hip_runtime.h>
#include <math.h>

// Problem constants (match reference)
constexpr int   B_    = 2048;
constexpr int   L_    = 8192;
constexpr int   G_    = 256;
constexpr float BETA_ = 0.01f;
constexpr float BIG_  = 1024.0f;      // y-flag encoding
constexpr int   PMAX  = L_ + G_ * 3;  // padded rank-space bound = 8960

typedef float f32x4 __attribute__((ext_vector_type(4)));
typedef int   i32x4 __attribute__((ext_vector_type(4)));

// log(sigmoid(-x)) = -softplus(x); HW transcendentals (absmax 0.0, R2-R7).
__device__ __forceinline__ float log_sigmoid_neg(float x) {
    return -(fmaxf(x, 0.0f) + __logf(1.0f + __expf(-fabsf(x))));
}

// ---------------------------------------------------------------------------
// k0: counting sort -> padded rank space (group extents rounded to 4 floats
// for aligned ds_read_b128 in phase 2; pad slots stay 0). Unchanged R6.
// ---------------------------------------------------------------------------
extern "C" __global__ __launch_bounds__(1024)
void build_rank_kernel(const int* __restrict__ group_ids,
                       int* __restrict__ g_offs,
                       unsigned short* __restrict__ g_rank)
{
    __shared__ int s_hist[G_];
    __shared__ int s_scan[G_];
    __shared__ int s_cur[G_];

    const int t = threadIdx.x;              // 0..1023

    if (t < G_) s_hist[t] = 0;

    int ids[8];
    #pragma unroll
    for (int i = 0; i < 8; ++i) ids[i] = group_ids[i * 1024 + t];

    __syncthreads();

    #pragma unroll
    for (int i = 0; i < 8; ++i) atomicAdd(&s_hist[ids[i]], 1);
    __syncthreads();

    if (t < G_) s_scan[t] = (s_hist[t] + 3) & ~3;
    __syncthreads();
    for (int off = 1; off < G_; off <<= 1) {
        int v = 0;
        if (t < G_ && t >= off) v = s_scan[t - off];
        __syncthreads();
        if (t < G_) s_scan[t] += v;
        __syncthreads();
    }

    if (t < G_) {
        const int excl = s_scan[t] - ((s_hist[t] + 3) & ~3);  // padded start
        s_cur[t]  = excl;
        g_offs[t] = excl;
    }
    if (t == 0) g_offs[G_] = s_scan[G_ - 1];
    __syncthreads();

    #pragma unroll
    for (int i = 0; i < 8; ++i) {
        const int l = i * 1024 + t;
        g_rank[l] = (unsigned short)atomicAdd(&s_cur[ids[i]], 1);
    }
}

// decode + transform + scatter one iteration's worth (4 elems/thread)
__device__ __forceinline__ void scat(float* __restrict__ s_row,
                                     const f32x4 x, const i32x4 y,
                                     const unsigned long long r) {
    s_row[(unsigned)( r        & 0xFFFF)] = log_sigmoid_neg(x.x) + (y.x ? BIG_ : 0.0f);
    s_row[(unsigned)((r >> 16) & 0xFFFF)] = log_sigmoid_neg(x.y) + (y.y ? BIG_ : 0.0f);
    s_row[(unsigned)((r >> 32) & 0xFFFF)] = log_sigmoid_neg(x.z) + (y.z ? BIG_ : 0.0f);
    s_row[(unsigned)( r >> 48          )] = log_sigmoid_neg(x.w) + (y.w ? BIG_ : 0.0f);
}

// ---------------------------------------------------------------------------
// Main kernel, one block (512 thr) per row. R6 structure (45us) + forced MLP:
// all 12 streaming loads issued back-to-back via asm volatile (compiler
// can't serialize them -- R3/R6 showed it otherwise emits load;wait;use with
// VGPR=24), consumed with descending s_waitcnt vmcnt(9/6/3/0) whose "+v"
// operand ties order the uses after each wait. 160 B/lane in flight.
// LDS = 35.9 KB (s_row only; no staging buffers).
// ---------------------------------------------------------------------------
extern "C" __global__ __launch_bounds__(512, 4)
void meta_loss_kernel(const float* __restrict__ logits,
                      const int*   __restrict__ true_y,
                      const int*   __restrict__ g_offs,
                      const unsigned short* __restrict__ g_rank,
                      float*       __restrict__ out)
{
    __shared__ alignas(16) float s_row[PMAX];   // 35 KB permuted encoded row
    __shared__ float s_part[8];

    const int t = threadIdx.x;                  // 0..511
    const int b = blockIdx.x;

    const float* xbase = logits + (size_t)b * L_;
    const int*   ybase = true_y + (size_t)b * L_;

    // group extents -- materialize NOW so their vmcnt is drained before the
    // asm load stream (otherwise our hand-counted vmcnt numbers break).
    int o0 = 0, o1 = 0;
    if (t < G_) { o0 = g_offs[t]; o1 = g_offs[t + 1]; }
    asm volatile("" : "+v"(o0), "+v"(o1));

    // zero-init padded row (pad slots must be 0)
    float4* s_row4 = (float4*)s_row;
    #pragma unroll
    for (int i = 0; i < (PMAX / 4 + 511) / 512; ++i) {
        const int j = i * 512 + t;
        if (j < PMAX / 4) s_row4[j] = make_float4(0.f, 0.f, 0.f, 0.f);
    }
    __syncthreads();

    // ---- Phase 1: 12 loads back-to-back, then staged consumption ----
    // thread t covers elements i*2048 + 4t .. +3 for i=0..3
    f32x4 x0, x1, x2, x3;
    i32x4 y0, y1, y2, y3;
    unsigned long long r0, r1, r2, r3;
    const unsigned xo = t * 16u;   // byte offset of float4/int4 in chunk
    const unsigned ro = t * 8u;    // byte offset of ushort4 in rank chunk

#define LD16(d, off, base) \
    asm volatile("global_load_dwordx4 %0, %1, %2" : "=v"(d) : "v"(off), "s"(base))
#define LD8(d, off, base) \
    asm volatile("global_load_dwordx2 %0, %1, %2" : "=v"(d) : "v"(off), "s"(base))

    LD16(x0, xo,           xbase); LD16(y0, xo,           ybase); LD8(r0, ro,           g_rank);
    LD16(x1, xo +  8192u,  xbase); LD16(y1, xo +  8192u,  ybase); LD8(r1, ro +  4096u,  g_rank);
    LD16(x2, xo + 16384u,  xbase); LD16(y2, xo + 16384u,  ybase); LD8(r2, ro +  8192u,  g_rank);
    LD16(x3, xo + 24576u,  xbase); LD16(y3, xo + 24576u,  ybase); LD8(r3, ro + 12288u,  g_rank);

    asm volatile("s_waitcnt vmcnt(9)" : "+v"(x0), "+v"(y0), "+v"(r0));
    scat(s_row, x0, y0, r0);
    asm volatile("s_waitcnt vmcnt(6)" : "+v"(x1), "+v"(y1), "+v"(r1));
    scat(s_row, x1, y1, r1);
    asm volatile("s_waitcnt vmcnt(3)" : "+v"(x2), "+v"(y2), "+v"(r2));
    scat(s_row, x2, y2, r2);
    asm volatile("s_waitcnt vmcnt(0)" : "+v"(x3), "+v"(y3), "+v"(r3));
    scat(s_row, x3, y3, r3);

#undef LD16
#undef LD8
    __syncthreads();

    // ---- Phase 2: vectorized contiguous per-group sum + decode (as R6) ----
    float term = 0.0f;
    if (t < G_) {
        float4 a4 = make_float4(0.f, 0.f, 0.f, 0.f);
        for (int j = o0; j < o1; j += 4) {
            const float4 v = *(const float4*)&s_row[j];
            a4.x += v.x; a4.y += v.y; a4.z += v.z; a4.w += v.w;
        }
        const float enc = (a4.x + a4.y) + (a4.z + a4.w);

        const int   k  = __float2int_rn(enc * (1.0f / BIG_));  // # true labels
        const float gl = enc - BIG_ * (float)k;                // sum log(1-sig)

        if (k != 0) {
            term = fmaxf(gl, -100.0f);                    // meta_y = 1: log(p)
        } else {
            // gl==0 (empty group) -> log1p(-1) = -inf -> clamped to -100
            term = fmaxf(log1pf(-__expf(gl)), -100.0f);   // meta_y = 0
        }
    }

    // block reduction (8 waves)
    #pragma unroll
    for (int off = 32; off > 0; off >>= 1)
        term += __shfl_down(term, off, 64);
    if ((t & 63) == 0) s_part[t >> 6] = term;
    __syncthreads();

    if (t == 0) {
        float s = 0.0f;
        #pragma unroll
        for (int w = 0; w < 8; ++w) s += s_part[w];
        atomicAdd(out, s * (-BETA_ / ((float)B_ * (float)G_)));
    }
}

extern "C" void kernel_launch(void* const* d_in, const int* in_sizes, int n_in,
                              void* d_out, int out_size, void* d_ws, size_t ws_size,
                              hipStream_t stream) {
    const float* logits    = (const float*)d_in[0];
    const int*   true_y    = (const int*)d_in[1];
    const int*   group_ids = (const int*)d_in[2];
    float*       out       = (float*)d_out;

    // workspace: [0, 2048) offs (257 ints used), [2048, 2048+16384) rank u16
    int*            g_offs = (int*)d_ws;
    unsigned short* g_rank = (unsigned short*)((char*)d_ws + 2048);

    hipMemsetAsync(out, 0, sizeof(float), stream);

    build_rank_kernel<<<1, 1024, 0, stream>>>(group_ids, g_offs, g_rank);
    meta_loss_kernel<<<B_, 512, 0, stream>>>(logits, true_y, g_offs, g_rank, out);
}